// Round 21
// baseline (91.839 us; speedup 1.0000x reference)
//
#include <hip/hip_runtime.h>
#include <float.h>

#define N_SEQ 2561
#define NPAD  2688          // 21 * 128 = 42 * 64 = 168 * 16
#define SEG   ((size_t)NPAD * 1024)
#define LOG2E 1.44269504088896340736f

typedef __attribute__((ext_vector_type(8))) short  short8;
typedef __attribute__((ext_vector_type(4))) short  s16x4;
typedef __attribute__((ext_vector_type(4))) float  f32x4;
typedef __attribute__((ext_vector_type(4))) unsigned int u32x4;
typedef __attribute__((ext_vector_type(4))) unsigned short u16x4;

__device__ __forceinline__ unsigned short f2bf(float f) {
  unsigned int u = __float_as_uint(f);
  u += 0x7FFFu + ((u >> 16) & 1u);
  return (unsigned short)(u >> 16);
}
__device__ __forceinline__ float bf2f(unsigned short v) {
  return __uint_as_float(((unsigned int)v) << 16);
}
__device__ __forceinline__ f32x4 mfma16(short8 a, short8 b, f32x4 c) {
  return __builtin_amdgcn_mfma_f32_16x16x32_bf16(a, b, c, 0, 0, 0);
}
__device__ __forceinline__ void load_lds16(const void* g, void* l) {
  __builtin_amdgcn_global_load_lds((const __attribute__((address_space(1))) void*)g,
                                   (__attribute__((address_space(3))) void*)l, 16, 0, 0);
}
__device__ __forceinline__ unsigned int cvt_pk_bf16(float a, float b) {
  unsigned int r;
  asm("v_cvt_pk_bf16_f32 %0, %1, %2" : "=v"(r) : "v"(a), "v"(b));
  return r;
}
__device__ __forceinline__ float fast_exp2(float x) {
  return __builtin_amdgcn_exp2f(x);
}

// ---------------- fused setup: q/k/v fp32->bf16, 4 weight transposes, mask table ----------------
__global__ __launch_bounds__(256) void cvt_all(const float* __restrict__ q, const float* __restrict__ k,
                                               const float* __restrict__ v,
                                               const float* __restrict__ W0, const float* __restrict__ W1,
                                               const float* __restrict__ W2, const float* __restrict__ W3,
                                               unsigned short* __restrict__ Xq, unsigned short* __restrict__ Xk,
                                               unsigned short* __restrict__ Xv,
                                               unsigned short* __restrict__ T0, unsigned short* __restrict__ T1,
                                               unsigned short* __restrict__ T2, unsigned short* __restrict__ T3,
                                               uint2* __restrict__ Mtab) {
  __shared__ float tls[64][65];
  const int bid = blockIdx.x;
  if (bid < 4032) {                       // x-conversion: 3 tensors x 1344 blocks
    const int by = bid / 1344, bx = bid - by * 1344;
    const float* src = (by == 0) ? q : (by == 1) ? k : v;
    unsigned short* dst = (by == 0) ? Xq : (by == 1) ? Xk : Xv;
    int idx = bx * 256 + threadIdx.x;
    size_t base = (size_t)idx * 8;
    int row = idx >> 7;
    short8 o;
    if (row < N_SEQ) {
      float4 a = *(const float4*)&src[base];
      float4 b = *(const float4*)&src[base + 4];
      o[0] = (short)f2bf(a.x); o[1] = (short)f2bf(a.y);
      o[2] = (short)f2bf(a.z); o[3] = (short)f2bf(a.w);
      o[4] = (short)f2bf(b.x); o[5] = (short)f2bf(b.y);
      o[6] = (short)f2bf(b.z); o[7] = (short)f2bf(b.w);
    } else {
      for (int j = 0; j < 8; ++j) o[j] = 0;
    }
    *(short8*)&dst[base] = o;
  } else if (bid < 5056) {                // weight transpose: 4 x 256 blocks
    const int b2 = bid - 4032;
    const int z = b2 >> 8, rem = b2 & 255;
    const int r0 = (rem >> 4) * 64, c0 = (rem & 15) * 64;
    const float* W; unsigned short* T; float scale = 1.0f;
    switch (z) {
      case 0: W = W0; T = T0; scale = 0.125f * LOG2E; break;   // 1/sqrt(64) * log2e into Wq
      case 1: W = W1; T = T1; break;
      case 2: W = W2; T = T2; break;
      default: W = W3; T = T3; break;
    }
    const int tid = threadIdx.x, tr = tid >> 4, tc = tid & 15;
#pragma unroll
    for (int u = 0; u < 4; ++u) {
      int row = tr + u * 16;
      float4 vv = *(const float4*)&W[(size_t)(r0 + row) * 1024 + c0 + tc * 4];
      tls[tc * 4 + 0][row] = vv.x; tls[tc * 4 + 1][row] = vv.y;
      tls[tc * 4 + 2][row] = vv.z; tls[tc * 4 + 3][row] = vv.w;
    }
    __syncthreads();
#pragma unroll
    for (int u = 0; u < 4; ++u) {
      int crow = tr + u * 16;
      u16x4 o;
#pragma unroll
      for (int j = 0; j < 4; ++j) o[j] = f2bf(tls[crow][tc * 4 + j] * scale);
      *(u16x4*)&T[(size_t)(c0 + crow) * 1024 + r0 + tc * 4] = o;
    }
  } else {                                // mask table: 4 blocks, 1024 entries (r x lane)
    const int idx = (bid - 5056) * 256 + threadIdx.x;
    const int r = idx >> 6, lane = idx & 63;
    const int lhi = lane >> 4, llo = lane & 15;
    const int rlo5 = min(max(r - 2, 0), 11);
    unsigned mpast = 0, mcur = 0;
#pragma unroll
    for (int n = 0; n < 6; ++n)
#pragma unroll
      for (int rr = 0; rr < 4; ++rr) {
        int s = n * 16 + lhi * 4 + rr;
        int u = rlo5 * 16 + s - 1;                 // kj offset within frame
        if (u < 0 || u > 255) continue;
        int rk = u >> 4, ck = u & 15;
        int dr = rk - r, dc = ck - llo;
        if (dr < -2 || dr > 2 || dc < -2 || dc > 2) continue;
        mpast |= 1u << (n * 4 + rr);
        if (dr < 0 || (dr == 0 && dc < 0)) mcur |= 1u << (n * 4 + rr);
      }
    Mtab[idx] = make_uint2(mpast, mcur);
  }
}

// ---------------- 128x64-tile 2-phase GEMM core (48 KB LDS -> 3 blocks/CU, BK=64) ----------------
__device__ __forceinline__ void stage_tile2(const unsigned short* A, const unsigned short* Bt,
                                            unsigned short* Asm, unsigned short* Bsm,
                                            int i0, int c0, int k0, int w, int srow, int scol) {
#pragma unroll
  for (int u = 0; u < 4; ++u) {
    int row = w * 32 + u * 8 + srow;
    load_lds16(&A[(size_t)(i0 + row) * 1024 + k0 + scol], &Asm[(w * 32 + u * 8) * 64]);
  }
#pragma unroll
  for (int u = 0; u < 2; ++u) {
    int row = w * 16 + u * 8 + srow;
    load_lds16(&Bt[(size_t)(c0 + row) * 1024 + k0 + scol], &Bsm[(w * 16 + u * 8) * 64]);
  }
}

// MODE 1: C per-head [16][NPAD][64] (row=seq, col=d_global)
// MODE 2: C d-tiled V^T [16][168][64][16] (row=d_global, col=seq-k)
template <int MODE>
__device__ __forceinline__ void gemm_core(const unsigned short* A, const unsigned short* Bt,
                                          unsigned short* C, int i0, int c0,
                                          unsigned short* Asm, unsigned short* Bsm) {
  const int tid = threadIdx.x, w = tid >> 6, lane = tid & 63;
  const int srow = lane >> 3;
  const int scol = ((lane & 7) * 8) ^ (srow << 3);
  const int llo = lane & 15, lhi = lane >> 4;
  f32x4 acc[2][4] = {};    // wave w: rows w*32..w*32+31, all 64 cols

  stage_tile2(A, Bt, Asm, Bsm, i0, c0, 0, w, srow, scol);

  for (int t = 0; t < 16; ++t) {
    __syncthreads();
    if (t < 15)
      stage_tile2(A, Bt, Asm + ((t + 1) & 1) * 8192, Bsm + ((t + 1) & 1) * 4096,
                  i0, c0, (t + 1) * 64, w, srow, scol);
    const unsigned short* Ab = Asm + (t & 1) * 8192;
    const unsigned short* Bb = Bsm + (t & 1) * 4096;
#pragma unroll
    for (int kk = 0; kk < 2; ++kk) {
      const int colel = kk * 32 + lhi * 8;
      short8 af[2], bf[4];
#pragma unroll
      for (int m = 0; m < 2; ++m) {
        int row = w * 32 + m * 16 + llo;
        af[m] = *(const short8*)&Ab[row * 64 + (colel ^ ((row & 7) << 3))];
      }
#pragma unroll
      for (int n = 0; n < 4; ++n) {
        int row = n * 16 + llo;
        bf[n] = *(const short8*)&Bb[row * 64 + (colel ^ ((row & 7) << 3))];
      }
#pragma unroll
      for (int m = 0; m < 2; ++m)
#pragma unroll
        for (int n = 0; n < 4; ++n)
          acc[m][n] = mfma16(af[m], bf[n], acc[m][n]);
    }
  }

#pragma unroll
  for (int m = 0; m < 2; ++m)
#pragma unroll
    for (int n = 0; n < 4; ++n) {
      const int col = c0 + n * 16 + llo;
#pragma unroll
      for (int r = 0; r < 4; ++r) {
        const int row = i0 + w * 32 + m * 16 + lhi * 4 + r;
        if (MODE == 1) {
          C[((size_t)(col >> 6) * NPAD + row) * 64 + (col & 63)] = f2bf(acc[m][n][r]);
        } else {
          C[(((size_t)(row >> 6) * 168 + (col >> 4)) * 64 + (row & 63)) * 16 + (col & 15)] = f2bf(acc[m][n][r]);
        }
      }
    }
}

__global__ __launch_bounds__(256) void proj3(const unsigned short* __restrict__ Xq, const unsigned short* __restrict__ WqT, unsigned short* __restrict__ Qh,
                                             const unsigned short* __restrict__ Xk, const unsigned short* __restrict__ WkT, unsigned short* __restrict__ Kh,
                                             const unsigned short* __restrict__ WvT, const unsigned short* __restrict__ Xv, unsigned short* __restrict__ Vt) {
  __shared__ unsigned short Asm[2 * 8192];   // 128 x 64 x 2 bufs (32 KB)
  __shared__ unsigned short Bsm[2 * 4096];   //  64 x 64 x 2 bufs (16 KB)
  int b = blockIdx.x;
  b = (b & 7) * 126 + (b >> 3);              // XCD-chunked swizzle (1008 = 126*8)
  if (b < 336) {
    int r = b;                               // Q: 21 row-tiles x 16 col-tiles
    gemm_core<1>(Xq, WqT, Qh, (r % 21) * 128, (r / 21) * 64, Asm, Bsm);
  } else if (b < 672) {
    int r = b - 336;
    gemm_core<1>(Xk, WkT, Kh, (r % 21) * 128, (r / 21) * 64, Asm, Bsm);
  } else {
    int r = b - 672;                         // V: 8 row-tiles x 42 col-tiles
    gemm_core<2>(WvT, Xv, Vt, (r % 8) * 128, (r / 8) * 64, Asm, Bsm);
  }
}

// ---------------- 64x64-tile fp32-out GEMM (outproj): 672 blocks for machine fill ----------------
__global__ __launch_bounds__(256) void outproj(const unsigned short* __restrict__ A, const unsigned short* __restrict__ Bt,
                                               float* __restrict__ out, const float* __restrict__ bias) {
  __shared__ unsigned short Asm[2 * 4096];   // 64 x 64 x 2 bufs
  __shared__ unsigned short Bsm[2 * 4096];   // 64 x 64 x 2 bufs
  int b = (blockIdx.x & 7) * 84 + (blockIdx.x >> 3);   // XCD-chunked swizzle (672 = 84*8)
  const int i0 = (b >> 4) * 64, c0 = (b & 15) * 64;
  const int tid = threadIdx.x, w = tid >> 6, lane = tid & 63;
  const int wr = w >> 1, wc = w & 1;
  const int srow = lane >> 3;
  const int scol = ((lane & 7) * 8) ^ (srow << 3);
  const int llo = lane & 15, lhi = lane >> 4;
  f32x4 acc[2][2] = {};

#define STAGE64(buf, k0)                                                                     \
  {                                                                                          \
    _Pragma("unroll")                                                                        \
    for (int u = 0; u < 2; ++u) {                                                            \
      int row = w * 16 + u * 8 + srow;                                                       \
      load_lds16(&A[(size_t)(i0 + row) * 1024 + (k0) + scol], &Asm[(buf) * 4096 + (w * 16 + u * 8) * 64]); \
      load_lds16(&Bt[(size_t)(c0 + row) * 1024 + (k0) + scol], &Bsm[(buf) * 4096 + (w * 16 + u * 8) * 64]); \
    }                                                                                        \
  }

  STAGE64(0, 0)
  for (int t = 0; t < 16; ++t) {
    __syncthreads();
    if (t < 15) STAGE64((t + 1) & 1, (t + 1) * 64)
    const unsigned short* Ab = Asm + (t & 1) * 4096;
    const unsigned short* Bb = Bsm + (t & 1) * 4096;
#pragma unroll
    for (int kk = 0; kk < 2; ++kk) {
      const int colel = kk * 32 + lhi * 8;
      short8 af[2], bf[2];
#pragma unroll
      for (int m = 0; m < 2; ++m) {
        int row = wr * 32 + m * 16 + llo;
        af[m] = *(const short8*)&Ab[row * 64 + (colel ^ ((row & 7) << 3))];
      }
#pragma unroll
      for (int n = 0; n < 2; ++n) {
        int row = wc * 32 + n * 16 + llo;
        bf[n] = *(const short8*)&Bb[row * 64 + (colel ^ ((row & 7) << 3))];
      }
#pragma unroll
      for (int m = 0; m < 2; ++m)
#pragma unroll
        for (int n = 0; n < 2; ++n)
          acc[m][n] = mfma16(af[m], bf[n], acc[m][n]);
    }
  }
#undef STAGE64

#pragma unroll
  for (int m = 0; m < 2; ++m)
#pragma unroll
    for (int n = 0; n < 2; ++n) {
      const int col = c0 + wc * 32 + n * 16 + llo;
      const float bb = bias[col];
#pragma unroll
      for (int r = 0; r < 4; ++r) {
        const int row = i0 + wr * 32 + m * 16 + lhi * 4 + r;
        if (row < N_SEQ) out[(size_t)row * 1024 + col] = acc[m][n][r] + bb;
      }
    }
}

// ---------------- frame-split span attention: K staged via global_load_lds (r20 optimum) ----------------
__global__ __launch_bounds__(256, 3) void attn_span7(const unsigned short* __restrict__ Qh,
                                                     const unsigned short* __restrict__ Kh,
                                                     const unsigned short* __restrict__ Vt,
                                                     unsigned short* __restrict__ Ob,
                                                     const uint2* __restrict__ Mtab) {
  __shared__ unsigned short Kbuf[4][6 * 16 * 64];   // 48 KB; reused as reduce buffer after barrier
  __shared__ float Ll[4][16];
  float (*Lacc)[64][17] = (float (*)[64][17]) & Kbuf[0][0];   // 13 KB alias
  float (*part)[64] = (float (*)[64]) & Kbuf[0][0];           // boundary-block alias

  if (blockIdx.x == 160) {                         // boundary rows for head h: parallel 4x64 design
    const int h = blockIdx.y;
    const int tid = threadIdx.x;
    const int dd = tid & 63, p = tid >> 6;
    float s = 0.f;
    for (int kb = p; kb < 168; kb += 4) {
      const unsigned short* vp = &Vt[(((size_t)h * 168 + kb) * 64 + dd) * 16];
      short8 a = *(const short8*)&vp[0];
      short8 bq = *(const short8*)&vp[8];
#pragma unroll
      for (int j = 0; j < 8; ++j)
        s += bf2f((unsigned short)a[j]) + bf2f((unsigned short)bq[j]);
    }
    part[p][dd] = s;
    __syncthreads();
    if (p == 0) {
      float tot = part[0][dd] + part[1][dd] + part[2][dd] + part[3][dd];
      Ob[(size_t)2560 * 1024 + h * 64 + dd] = f2bf(tot * (1.0f / 2561.0f));  // fully-masked row
      Ob[h * 64 + dd] = Vt[(((size_t)h * 168) * 64 + dd) * 16];              // row 0 = V[0]
    }
    return;
  }

  int bid = blockIdx.x + blockIdx.y * 160;         // 0..2559
  bid = (bid & 7) * 320 + (bid >> 3);              // XCD chunk: 2 heads per XCD
  const int qg = bid % 160, h = bid / 160;
  const int w = threadIdx.x >> 6, lane = threadIdx.x & 63;
  const int lhi = lane >> 4, llo = lane & 15;
  const int t = qg >> 4, r = qg & 15;
  const int rlo5 = min(max(r - 2, 0), 11);
  const int f = t - 3 + w;

  const uint2 mm = Mtab[(r << 6) + lane];
  const unsigned msk = (w == 3) ? mm.y : mm.x;

  f32x4 acc[4] = {};     // acc[n2]: D[q-row=lhi*4+rr][d=n2*16+llo] (this wave's frame)
  float l = 0.f;

  if (f >= 0) {                                    // wave-uniform
    const int jb0 = f * 256 + rlo5 * 16;

    // ---- K staging via DMA (12 instr, no VGPR dest, pre-swizzled source) ----
    unsigned short* Kw = &Kbuf[w][0];
    const int srow8 = lane >> 3;                   // 0..7
    const int scolK = ((lane & 7) * 8) ^ (srow8 << 3);
    const unsigned short* kgbase = &Kh[((size_t)h * NPAD + jb0) * 64];
#pragma unroll
    for (int n = 0; n < 6; ++n)
#pragma unroll
      for (int u = 0; u < 2; ++u) {
        const int row0 = n * 16 + u * 8;
        load_lds16(kgbase + (size_t)(row0 + srow8) * 64 + scolK, &Kw[row0 * 64]);
      }

    // ---- Q + V register loads (issue in the same window) ----
    const unsigned short* qp = &Qh[((size_t)h * NPAD + qg * 16 + llo) * 64 + lhi * 8];
    short8 qf0 = *(const short8*)&qp[0];
    short8 qf1 = *(const short8*)&qp[32];

    s16x4 vv[3][4][2];
    const size_t tb = (size_t)h * 168 + (jb0 >> 4);
#pragma unroll
    for (int kk = 0; kk < 3; ++kk)
#pragma unroll
      for (int n2 = 0; n2 < 4; ++n2) {
        vv[kk][n2][0] = *(const s16x4*)&Vt[((tb + kk * 2)     * 64 + n2 * 16 + llo) * 16 + lhi * 4];
        vv[kk][n2][1] = *(const s16x4*)&Vt[((tb + kk * 2 + 1) * 64 + n2 * 16 + llo) * 16 + lhi * 4];
      }
    asm volatile("s_waitcnt vmcnt(0)" ::: "memory");   // all DMA + loads landed
    __builtin_amdgcn_sched_barrier(0);

    // ---- compute: QK from LDS, softmax, PV from registers ----
    __builtin_amdgcn_s_setprio(1);
    float p[6][4];
#pragma unroll
    for (int n = 0; n < 6; ++n) {
      const int rowb = (n * 16 + llo) * 64;
      const int sw = (llo & 7) << 3;
      short8 kf0 = *(const short8*)&Kw[rowb + ((lhi * 8) ^ sw)];
      short8 kf1 = *(const short8*)&Kw[rowb + ((32 + lhi * 8) ^ sw)];
      f32x4 z = {0.f, 0.f, 0.f, 0.f};
      z = mfma16(kf0, qf0, z);
      z = mfma16(kf1, qf1, z);
#pragma unroll
      for (int rr = 0; rr < 4; ++rr) {
        float pv = ((msk >> (n * 4 + rr)) & 1u) ? fast_exp2(z[rr]) : 0.f;
        p[n][rr] = pv;
        l += pv;
      }
    }

#pragma unroll
    for (int kk = 0; kk < 3; ++kk) {
      const int n0 = kk * 2;
      u32x4 pw;
      pw[0] = cvt_pk_bf16(p[n0][0], p[n0][1]);
      pw[1] = cvt_pk_bf16(p[n0][2], p[n0][3]);
      pw[2] = cvt_pk_bf16(p[n0 + 1][0], p[n0 + 1][1]);
      pw[3] = cvt_pk_bf16(p[n0 + 1][2], p[n0 + 1][3]);
      short8 pf = __builtin_bit_cast(short8, pw);
#pragma unroll
      for (int n2 = 0; n2 < 4; ++n2) {
        short8 vf = __builtin_shufflevector(vv[kk][n2][0], vv[kk][n2][1], 0, 1, 2, 3, 4, 5, 6, 7);
        acc[n2] = mfma16(pf, vf, acc[n2]);
      }
    }
    __builtin_amdgcn_s_setprio(0);
  }

  // in-wave l reduce; then cross-wave combine via the ALIASED LDS buffer (barrier first)
  l += __shfl_xor(l, 16);
  l += __shfl_xor(l, 32);
  __syncthreads();
  if (lhi == 0) Ll[w][llo] = l;
  if (w > 0) {
#pragma unroll
    for (int n2 = 0; n2 < 4; ++n2)
#pragma unroll
      for (int rr = 0; rr < 4; ++rr)
        Lacc[w - 1][lane][n2 * 4 + rr] = acc[n2][rr];
  }
  __syncthreads();
  if (w == 0) {
    const float lt = Ll[0][llo] + Ll[1][llo] + Ll[2][llo] + Ll[3][llo];
    float li[4];
#pragma unroll
    for (int rr = 0; rr < 4; ++rr) li[rr] = 1.0f / __shfl(lt, lhi * 4 + rr);
#pragma unroll
    for (int rr = 0; rr < 4; ++rr) {
      const int row = qg * 16 + lhi * 4 + rr;
      if (row == 0) continue;                       // row 0 owned by the boundary block
#pragma unroll
      for (int n2 = 0; n2 < 4; ++n2) {
        float s = acc[n2][rr] + Lacc[0][lane][n2 * 4 + rr]
                              + Lacc[1][lane][n2 * 4 + rr]
                              + Lacc[2][lane][n2 * 4 + rr];
        Ob[(size_t)row * 1024 + h * 64 + n2 * 16 + llo] = f2bf(s * li[rr]);
      }
    }
  }
}

extern "C" void kernel_launch(void* const* d_in, const int* in_sizes, int n_in,
                              void* d_out, int out_size, void* d_ws, size_t ws_size,
                              hipStream_t stream) {
  const float* q  = (const float*)d_in[0];
  const float* k  = (const float*)d_in[1];
  const float* v  = (const float*)d_in[2];
  const float* Wq = (const float*)d_in[3];
  const float* Wk = (const float*)d_in[4];
  const float* Wv = (const float*)d_in[5];
  const float* Wo = (const float*)d_in[6];
  const float* bo = (const float*)d_in[7];

  unsigned short* ws = (unsigned short*)d_ws;
  const size_t MW = (size_t)1024 * 1024;
  unsigned short* Xq  = ws;
  unsigned short* Xk  = ws + SEG;
  unsigned short* Xv  = ws + 2 * SEG;
  unsigned short* Qh  = ws + 3 * SEG;  // [16][NPAD][64]
  unsigned short* Kh  = ws + 4 * SEG;  // [16][NPAD][64]
  unsigned short* Vt  = ws + 5 * SEG;  // [16][168][64][16]
  unsigned short* WqT = ws + 6 * SEG;
  unsigned short* WkT = WqT + MW;
  unsigned short* WvT = WqT + 2 * MW;
  unsigned short* WoT = WqT + 3 * MW;
  uint2* Mtab = (uint2*)(WqT + 4 * MW);
  unsigned short* ObB = Xq;            // reuse Xq after projections

  cvt_all<<<5060, 256, 0, stream>>>(q, k, v, Wq, Wk, Wv, Wo, Xq, Xk, Xv, WqT, WkT, WvT, WoT, Mtab);

  proj3<<<1008, 256, 0, stream>>>(Xq, WqT, Qh, Xk, WkT, Kh, WvT, Xv, Vt);

  attn_span7<<<dim3(161, 16), 256, 0, stream>>>(Qh, Kh, Vt, ObB, Mtab);

  outproj<<<672, 256, 0, stream>>>(ObB, WoT, (float*)d_out, bo);
}

// Round 22
// 84.288 us; speedup vs baseline: 1.0896x; 1.0896x over previous
//
#include <hip/hip_runtime.h>
#include <float.h>

#define N_SEQ 2561
#define NPAD  2688          // 21 * 128 = 42 * 64 = 168 * 16
#define SEG   ((size_t)NPAD * 1024)
#define LOG2E 1.44269504088896340736f

typedef __attribute__((ext_vector_type(8))) short  short8;
typedef __attribute__((ext_vector_type(4))) short  s16x4;
typedef __attribute__((ext_vector_type(4))) float  f32x4;
typedef __attribute__((ext_vector_type(4))) unsigned int u32x4;
typedef __attribute__((ext_vector_type(4))) unsigned short u16x4;

__device__ __forceinline__ unsigned short f2bf(float f) {
  unsigned int u = __float_as_uint(f);
  u += 0x7FFFu + ((u >> 16) & 1u);
  return (unsigned short)(u >> 16);
}
__device__ __forceinline__ float bf2f(unsigned short v) {
  return __uint_as_float(((unsigned int)v) << 16);
}
__device__ __forceinline__ f32x4 mfma16(short8 a, short8 b, f32x4 c) {
  return __builtin_amdgcn_mfma_f32_16x16x32_bf16(a, b, c, 0, 0, 0);
}
__device__ __forceinline__ void load_lds16(const void* g, void* l) {
  __builtin_amdgcn_global_load_lds((const __attribute__((address_space(1))) void*)g,
                                   (__attribute__((address_space(3))) void*)l, 16, 0, 0);
}
__device__ __forceinline__ unsigned int cvt_pk_bf16(float a, float b) {
  unsigned int r;
  asm("v_cvt_pk_bf16_f32 %0, %1, %2" : "=v"(r) : "v"(a), "v"(b));
  return r;
}
__device__ __forceinline__ float fast_exp2(float x) {
  return __builtin_amdgcn_exp2f(x);
}

// ---------------- fused setup: q/k/v fp32->bf16, 4 weight transposes, mask table ----------------
__global__ __launch_bounds__(256) void cvt_all(const float* __restrict__ q, const float* __restrict__ k,
                                               const float* __restrict__ v,
                                               const float* __restrict__ W0, const float* __restrict__ W1,
                                               const float* __restrict__ W2, const float* __restrict__ W3,
                                               unsigned short* __restrict__ Xq, unsigned short* __restrict__ Xk,
                                               unsigned short* __restrict__ Xv,
                                               unsigned short* __restrict__ T0, unsigned short* __restrict__ T1,
                                               unsigned short* __restrict__ T2, unsigned short* __restrict__ T3,
                                               uint2* __restrict__ Mtab) {
  __shared__ float tls[64][65];
  const int bid = blockIdx.x;
  if (bid < 4032) {                       // x-conversion: 3 tensors x 1344 blocks
    const int by = bid / 1344, bx = bid - by * 1344;
    const float* src = (by == 0) ? q : (by == 1) ? k : v;
    unsigned short* dst = (by == 0) ? Xq : (by == 1) ? Xk : Xv;
    int idx = bx * 256 + threadIdx.x;
    size_t base = (size_t)idx * 8;
    int row = idx >> 7;
    short8 o;
    if (row < N_SEQ) {
      float4 a = *(const float4*)&src[base];
      float4 b = *(const float4*)&src[base + 4];
      o[0] = (short)f2bf(a.x); o[1] = (short)f2bf(a.y);
      o[2] = (short)f2bf(a.z); o[3] = (short)f2bf(a.w);
      o[4] = (short)f2bf(b.x); o[5] = (short)f2bf(b.y);
      o[6] = (short)f2bf(b.z); o[7] = (short)f2bf(b.w);
    } else {
      for (int j = 0; j < 8; ++j) o[j] = 0;
    }
    *(short8*)&dst[base] = o;
  } else if (bid < 5056) {                // weight transpose: 4 x 256 blocks
    const int b2 = bid - 4032;
    const int z = b2 >> 8, rem = b2 & 255;
    const int r0 = (rem >> 4) * 64, c0 = (rem & 15) * 64;
    const float* W; unsigned short* T; float scale = 1.0f;
    switch (z) {
      case 0: W = W0; T = T0; scale = 0.125f * LOG2E; break;   // 1/sqrt(64) * log2e into Wq
      case 1: W = W1; T = T1; break;
      case 2: W = W2; T = T2; break;
      default: W = W3; T = T3; break;
    }
    const int tid = threadIdx.x, tr = tid >> 4, tc = tid & 15;
#pragma unroll
    for (int u = 0; u < 4; ++u) {
      int row = tr + u * 16;
      float4 vv = *(const float4*)&W[(size_t)(r0 + row) * 1024 + c0 + tc * 4];
      tls[tc * 4 + 0][row] = vv.x; tls[tc * 4 + 1][row] = vv.y;
      tls[tc * 4 + 2][row] = vv.z; tls[tc * 4 + 3][row] = vv.w;
    }
    __syncthreads();
#pragma unroll
    for (int u = 0; u < 4; ++u) {
      int crow = tr + u * 16;
      u16x4 o;
#pragma unroll
      for (int j = 0; j < 4; ++j) o[j] = f2bf(tls[crow][tc * 4 + j] * scale);
      *(u16x4*)&T[(size_t)(c0 + crow) * 1024 + r0 + tc * 4] = o;
    }
  } else {                                // mask table: 4 blocks, 1024 entries (r x lane)
    const int idx = (bid - 5056) * 256 + threadIdx.x;
    const int r = idx >> 6, lane = idx & 63;
    const int lhi = lane >> 4, llo = lane & 15;
    const int rlo5 = min(max(r - 2, 0), 11);
    unsigned mpast = 0, mcur = 0;
#pragma unroll
    for (int n = 0; n < 6; ++n)
#pragma unroll
      for (int rr = 0; rr < 4; ++rr) {
        int s = n * 16 + lhi * 4 + rr;
        int u = rlo5 * 16 + s - 1;                 // kj offset within frame
        if (u < 0 || u > 255) continue;
        int rk = u >> 4, ck = u & 15;
        int dr = rk - r, dc = ck - llo;
        if (dr < -2 || dr > 2 || dc < -2 || dc > 2) continue;
        mpast |= 1u << (n * 4 + rr);
        if (dr < 0 || (dr == 0 && dc < 0)) mcur |= 1u << (n * 4 + rr);
      }
    Mtab[idx] = make_uint2(mpast, mcur);
  }
}

// ---------------- 128x128 2-phase GEMM core ----------------
__device__ __forceinline__ void stage_tile(const unsigned short* A, const unsigned short* Bt,
                                           unsigned short* Asm, unsigned short* Bsm,
                                           int i0, int c0, int k0, int w, int srow, int scol) {
#pragma unroll
  for (int u = 0; u < 4; ++u) {
    int row = w * 32 + u * 8 + srow;
    load_lds16(&A [(size_t)(i0 + row) * 1024 + k0 + scol], &Asm[(w * 32 + u * 8) * 64]);
    load_lds16(&Bt[(size_t)(c0 + row) * 1024 + k0 + scol], &Bsm[(w * 32 + u * 8) * 64]);
  }
}

// MODE 1: C per-head [16][NPAD][64] (row=seq, col=d_global)
// MODE 2: C d-tiled V^T [16][168][64][16] (row=d_global, col=seq-k)
template <int MODE>
__device__ __forceinline__ void gemm_core(const unsigned short* A, const unsigned short* Bt,
                                          unsigned short* C, int i0, int c0,
                                          unsigned short* Asm, unsigned short* Bsm) {
  const int tid = threadIdx.x, w = tid >> 6, lane = tid & 63;
  const int wr = w >> 1, wc = w & 1;
  const int srow = lane >> 3;
  const int scol = ((lane & 7) * 8) ^ (srow << 3);
  f32x4 acc[4][4] = {};

  stage_tile(A, Bt, Asm, Bsm, i0, c0, 0, w, srow, scol);

  for (int t = 0; t < 16; ++t) {
    __syncthreads();
    if (t < 15)
      stage_tile(A, Bt, Asm + ((t + 1) & 1) * 8192, Bsm + ((t + 1) & 1) * 8192,
                 i0, c0, (t + 1) * 64, w, srow, scol);
    const unsigned short* Ab = Asm + (t & 1) * 8192;
    const unsigned short* Bb = Bsm + (t & 1) * 8192;
#pragma unroll
    for (int kk = 0; kk < 2; ++kk) {
      const int colel = kk * 32 + (lane >> 4) * 8;
      short8 af[4], bf[4];
#pragma unroll
      for (int m = 0; m < 4; ++m) {
        int row = wr * 64 + m * 16 + (lane & 15);
        af[m] = *(const short8*)&Ab[row * 64 + (colel ^ ((row & 7) << 3))];
      }
#pragma unroll
      for (int n = 0; n < 4; ++n) {
        int row = wc * 64 + n * 16 + (lane & 15);
        bf[n] = *(const short8*)&Bb[row * 64 + (colel ^ ((row & 7) << 3))];
      }
#pragma unroll
      for (int m = 0; m < 4; ++m)
#pragma unroll
        for (int n = 0; n < 4; ++n)
          acc[m][n] = mfma16(af[m], bf[n], acc[m][n]);
    }
  }

#pragma unroll
  for (int m = 0; m < 4; ++m)
#pragma unroll
    for (int n = 0; n < 4; ++n) {
      const int col = c0 + wc * 64 + n * 16 + (lane & 15);
#pragma unroll
      for (int r = 0; r < 4; ++r) {
        const int row = i0 + wr * 64 + m * 16 + (lane >> 4) * 4 + r;
        if (MODE == 1) {
          C[((size_t)(col >> 6) * NPAD + row) * 64 + (col & 63)] = f2bf(acc[m][n][r]);
        } else {
          C[(((size_t)(row >> 6) * 168 + (col >> 4)) * 64 + (row & 63)) * 16 + (col & 15)] = f2bf(acc[m][n][r]);
        }
      }
    }
}

__global__ __launch_bounds__(256) void proj3(const unsigned short* __restrict__ Xq, const unsigned short* __restrict__ WqT, unsigned short* __restrict__ Qh,
                                             const unsigned short* __restrict__ Xk, const unsigned short* __restrict__ WkT, unsigned short* __restrict__ Kh,
                                             const unsigned short* __restrict__ WvT, const unsigned short* __restrict__ Xv, unsigned short* __restrict__ Vt) {
  __shared__ unsigned short Asm[2 * 8192];
  __shared__ unsigned short Bsm[2 * 8192];
  int b = blockIdx.x;
  b = (b & 7) * 63 + (b >> 3);               // XCD-chunked swizzle (504 = 63*8)
  if (b < 168) {
    int r = b;
    gemm_core<1>(Xq, WqT, Qh, (r >> 3) * 128, (r & 7) * 128, Asm, Bsm);
  } else if (b < 336) {
    int r = b - 168;
    gemm_core<1>(Xk, WkT, Kh, (r >> 3) * 128, (r & 7) * 128, Asm, Bsm);
  } else {
    int r = b - 336;
    gemm_core<2>(WvT, Xv, Vt, (r / 21) * 128, (r % 21) * 128, Asm, Bsm);
  }
}

// ---------------- 64x64-tile fp32-out GEMM (outproj): 672 blocks for machine fill ----------------
__global__ __launch_bounds__(256) void outproj(const unsigned short* __restrict__ A, const unsigned short* __restrict__ Bt,
                                               float* __restrict__ out, const float* __restrict__ bias) {
  __shared__ unsigned short Asm[2 * 4096];   // 64 x 64 x 2 bufs
  __shared__ unsigned short Bsm[2 * 4096];   // 64 x 64 x 2 bufs
  int b = (blockIdx.x & 7) * 84 + (blockIdx.x >> 3);   // XCD-chunked swizzle (672 = 84*8)
  const int i0 = (b >> 4) * 64, c0 = (b & 15) * 64;
  const int tid = threadIdx.x, w = tid >> 6, lane = tid & 63;
  const int wr = w >> 1, wc = w & 1;
  const int srow = lane >> 3;
  const int scol = ((lane & 7) * 8) ^ (srow << 3);
  const int llo = lane & 15, lhi = lane >> 4;
  f32x4 acc[2][2] = {};

#define STAGE64(buf, k0)                                                                     \
  {                                                                                          \
    _Pragma("unroll")                                                                        \
    for (int u = 0; u < 2; ++u) {                                                            \
      int row = w * 16 + u * 8 + srow;                                                       \
      load_lds16(&A[(size_t)(i0 + row) * 1024 + (k0) + scol], &Asm[(buf) * 4096 + (w * 16 + u * 8) * 64]); \
      load_lds16(&Bt[(size_t)(c0 + row) * 1024 + (k0) + scol], &Bsm[(buf) * 4096 + (w * 16 + u * 8) * 64]); \
    }                                                                                        \
  }

  STAGE64(0, 0)
  for (int t = 0; t < 16; ++t) {
    __syncthreads();
    if (t < 15) STAGE64((t + 1) & 1, (t + 1) * 64)
    const unsigned short* Ab = Asm + (t & 1) * 4096;
    const unsigned short* Bb = Bsm + (t & 1) * 4096;
#pragma unroll
    for (int kk = 0; kk < 2; ++kk) {
      const int colel = kk * 32 + lhi * 8;
      short8 af[2], bf[2];
#pragma unroll
      for (int m = 0; m < 2; ++m) {
        int row = wr * 32 + m * 16 + llo;
        af[m] = *(const short8*)&Ab[row * 64 + (colel ^ ((row & 7) << 3))];
      }
#pragma unroll
      for (int n = 0; n < 2; ++n) {
        int row = wc * 32 + n * 16 + llo;
        bf[n] = *(const short8*)&Bb[row * 64 + (colel ^ ((row & 7) << 3))];
      }
#pragma unroll
      for (int m = 0; m < 2; ++m)
#pragma unroll
        for (int n = 0; n < 2; ++n)
          acc[m][n] = mfma16(af[m], bf[n], acc[m][n]);
    }
  }
#undef STAGE64

#pragma unroll
  for (int m = 0; m < 2; ++m)
#pragma unroll
    for (int n = 0; n < 2; ++n) {
      const int col = c0 + wc * 32 + n * 16 + llo;
      const float bb = bias[col];
#pragma unroll
      for (int r = 0; r < 4; ++r) {
        const int row = i0 + wr * 32 + m * 16 + lhi * 4 + r;
        if (row < N_SEQ) out[(size_t)row * 1024 + col] = acc[m][n][r] + bb;
      }
    }
}

// ---------------- frame-split span attention: K staged via global_load_lds (DMA, no VGPR dest)
// DMA cannot be sunk by the register allocator (r9/r12/r13 pathology); one vmcnt(0) wait gives a
// single latency exposure for the QK path. LDS K-buffer (48 KB) aliased with the reduce buffer.
__global__ __launch_bounds__(256, 3) void attn_span7(const unsigned short* __restrict__ Qh,
                                                     const unsigned short* __restrict__ Kh,
                                                     const unsigned short* __restrict__ Vt,
                                                     unsigned short* __restrict__ Ob,
                                                     const uint2* __restrict__ Mtab) {
  __shared__ unsigned short Kbuf[4][6 * 16 * 64];   // 48 KB; reused as reduce buffer after barrier
  __shared__ float Ll[4][16];
  float (*Lacc)[64][17] = (float (*)[64][17]) & Kbuf[0][0];   // 13 KB alias
  float (*part)[64] = (float (*)[64]) & Kbuf[0][0];           // boundary-block alias

  if (blockIdx.x == 160) {                         // boundary rows for head h: parallel 4x64 design
    const int h = blockIdx.y;
    const int tid = threadIdx.x;
    const int dd = tid & 63, p = tid >> 6;
    float s = 0.f;
    for (int kb = p; kb < 168; kb += 4) {
      const unsigned short* vp = &Vt[(((size_t)h * 168 + kb) * 64 + dd) * 16];
      short8 a = *(const short8*)&vp[0];
      short8 bq = *(const short8*)&vp[8];
#pragma unroll
      for (int j = 0; j < 8; ++j)
        s += bf2f((unsigned short)a[j]) + bf2f((unsigned short)bq[j]);
    }
    part[p][dd] = s;
    __syncthreads();
    if (p == 0) {
      float tot = part[0][dd] + part[1][dd] + part[2][dd] + part[3][dd];
      Ob[(size_t)2560 * 1024 + h * 64 + dd] = f2bf(tot * (1.0f / 2561.0f));  // fully-masked row
      Ob[h * 64 + dd] = Vt[(((size_t)h * 168) * 64 + dd) * 16];              // row 0 = V[0]
    }
    return;
  }

  int bid = blockIdx.x + blockIdx.y * 160;         // 0..2559
  bid = (bid & 7) * 320 + (bid >> 3);              // XCD chunk: 2 heads per XCD
  const int qg = bid % 160, h = bid / 160;
  const int w = threadIdx.x >> 6, lane = threadIdx.x & 63;
  const int lhi = lane >> 4, llo = lane & 15;
  const int t = qg >> 4, r = qg & 15;
  const int rlo5 = min(max(r - 2, 0), 11);
  const int f = t - 3 + w;

  const uint2 mm = Mtab[(r << 6) + lane];
  const unsigned msk = (w == 3) ? mm.y : mm.x;

  f32x4 acc[4] = {};     // acc[n2]: D[q-row=lhi*4+rr][d=n2*16+llo] (this wave's frame)
  float l = 0.f;

  if (f >= 0) {                                    // wave-uniform
    const int jb0 = f * 256 + rlo5 * 16;

    // ---- K staging via DMA (12 instr, no VGPR dest, pre-swizzled source) ----
    unsigned short* Kw = &Kbuf[w][0];
    const int srow8 = lane >> 3;                   // 0..7
    const int scolK = ((lane & 7) * 8) ^ (srow8 << 3);
    const unsigned short* kgbase = &Kh[((size_t)h * NPAD + jb0) * 64];
#pragma unroll
    for (int n = 0; n < 6; ++n)
#pragma unroll
      for (int u = 0; u < 2; ++u) {
        const int row0 = n * 16 + u * 8;
        load_lds16(kgbase + (size_t)(row0 + srow8) * 64 + scolK, &Kw[row0 * 64]);
      }

    // ---- Q + V register loads (issue in the same window) ----
    const unsigned short* qp = &Qh[((size_t)h * NPAD + qg * 16 + llo) * 64 + lhi * 8];
    short8 qf0 = *(const short8*)&qp[0];
    short8 qf1 = *(const short8*)&qp[32];

    s16x4 vv[3][4][2];
    const size_t tb = (size_t)h * 168 + (jb0 >> 4);
#pragma unroll
    for (int kk = 0; kk < 3; ++kk)
#pragma unroll
      for (int n2 = 0; n2 < 4; ++n2) {
        vv[kk][n2][0] = *(const s16x4*)&Vt[((tb + kk * 2)     * 64 + n2 * 16 + llo) * 16 + lhi * 4];
        vv[kk][n2][1] = *(const s16x4*)&Vt[((tb + kk * 2 + 1) * 64 + n2 * 16 + llo) * 16 + lhi * 4];
      }
    asm volatile("s_waitcnt vmcnt(0)" ::: "memory");   // all DMA + loads landed
    __builtin_amdgcn_sched_barrier(0);

    // ---- compute: QK from LDS, softmax, PV from registers ----
    __builtin_amdgcn_s_setprio(1);
    float p[6][4];
#pragma unroll
    for (int n = 0; n < 6; ++n) {
      const int rowb = (n * 16 + llo) * 64;
      const int sw = (llo & 7) << 3;
      short8 kf0 = *(const short8*)&Kw[rowb + ((lhi * 8) ^ sw)];
      short8 kf1 = *(const short8*)&Kw[rowb + ((32 + lhi * 8) ^ sw)];
      f32x4 z = {0.f, 0.f, 0.f, 0.f};
      z = mfma16(kf0, qf0, z);
      z = mfma16(kf1, qf1, z);
#pragma unroll
      for (int rr = 0; rr < 4; ++rr) {
        float pv = ((msk >> (n * 4 + rr)) & 1u) ? fast_exp2(z[rr]) : 0.f;
        p[n][rr] = pv;
        l += pv;
      }
    }

#pragma unroll
    for (int kk = 0; kk < 3; ++kk) {
      const int n0 = kk * 2;
      u32x4 pw;
      pw[0] = cvt_pk_bf16(p[n0][0], p[n0][1]);
      pw[1] = cvt_pk_bf16(p[n0][2], p[n0][3]);
      pw[2] = cvt_pk_bf16(p[n0 + 1][0], p[n0 + 1][1]);
      pw[3] = cvt_pk_bf16(p[n0 + 1][2], p[n0 + 1][3]);
      short8 pf = __builtin_bit_cast(short8, pw);
#pragma unroll
      for (int n2 = 0; n2 < 4; ++n2) {
        short8 vf = __builtin_shufflevector(vv[kk][n2][0], vv[kk][n2][1], 0, 1, 2, 3, 4, 5, 6, 7);
        acc[n2] = mfma16(pf, vf, acc[n2]);
      }
    }
    __builtin_amdgcn_s_setprio(0);
  }

  // in-wave l reduce; then cross-wave combine via the ALIASED LDS buffer (barrier first:
  // Lacc overlaps Kbuf[0..1], owned as K by waves 0/1 until they finish QK)
  l += __shfl_xor(l, 16);
  l += __shfl_xor(l, 32);
  __syncthreads();
  if (lhi == 0) Ll[w][llo] = l;
  if (w > 0) {
#pragma unroll
    for (int n2 = 0; n2 < 4; ++n2)
#pragma unroll
      for (int rr = 0; rr < 4; ++rr)
        Lacc[w - 1][lane][n2 * 4 + rr] = acc[n2][rr];
  }
  __syncthreads();
  if (w == 0) {
    const float lt = Ll[0][llo] + Ll[1][llo] + Ll[2][llo] + Ll[3][llo];
    float li[4];
#pragma unroll
    for (int rr = 0; rr < 4; ++rr) li[rr] = 1.0f / __shfl(lt, lhi * 4 + rr);
#pragma unroll
    for (int rr = 0; rr < 4; ++rr) {
      const int row = qg * 16 + lhi * 4 + rr;
      if (row == 0) continue;                       // row 0 owned by the boundary block
#pragma unroll
      for (int n2 = 0; n2 < 4; ++n2) {
        float s = acc[n2][rr] + Lacc[0][lane][n2 * 4 + rr]
                              + Lacc[1][lane][n2 * 4 + rr]
                              + Lacc[2][lane][n2 * 4 + rr];
        Ob[(size_t)row * 1024 + h * 64 + n2 * 16 + llo] = f2bf(s * li[rr]);
      }
    }
  }
}

extern "C" void kernel_launch(void* const* d_in, const int* in_sizes, int n_in,
                              void* d_out, int out_size, void* d_ws, size_t ws_size,
                              hipStream_t stream) {
  const float* q  = (const float*)d_in[0];
  const float* k  = (const float*)d_in[1];
  const float* v  = (const float*)d_in[2];
  const float* Wq = (const float*)d_in[3];
  const float* Wk = (const float*)d_in[4];
  const float* Wv = (const float*)d_in[5];
  const float* Wo = (const float*)d_in[6];
  const float* bo = (const float*)d_in[7];

  unsigned short* ws = (unsigned short*)d_ws;
  const size_t MW = (size_t)1024 * 1024;
  unsigned short* Xq  = ws;
  unsigned short* Xk  = ws + SEG;
  unsigned short* Xv  = ws + 2 * SEG;
  unsigned short* Qh  = ws + 3 * SEG;  // [16][NPAD][64]
  unsigned short* Kh  = ws + 4 * SEG;  // [16][NPAD][64]
  unsigned short* Vt  = ws + 5 * SEG;  // [16][168][64][16]
  unsigned short* WqT = ws + 6 * SEG;
  unsigned short* WkT = WqT + MW;
  unsigned short* WvT = WqT + 2 * MW;
  unsigned short* WoT = WqT + 3 * MW;
  uint2* Mtab = (uint2*)(WqT + 4 * MW);
  unsigned short* ObB = Xq;            // reuse Xq after projections

  cvt_all<<<5060, 256, 0, stream>>>(q, k, v, Wq, Wk, Wv, Wo, Xq, Xk, Xv, WqT, WkT, WvT, WoT, Mtab);

  proj3<<<504, 256, 0, stream>>>(Xq, WqT, Qh, Xk, WkT, Kh, WvT, Xv, Vt);

  attn_span7<<<dim3(161, 16), 256, 0, stream>>>(Qh, Kh, Vt, ObB, Mtab);

  outproj<<<672, 256, 0, stream>>>(ObB, WoT, (float*)d_out, bo);
}